// Round 1
// 223.201 us; speedup vs baseline: 1.4238x; 1.4238x over previous
//
#include <hip/hip_runtime.h>
#include <math.h>

// ConvSlimCapsule3D fused, round 5.
// Shapes fixed: B=2, in_dim=8, in_atoms=16, D=H=W=32, out_dim=8, out_atoms=16, k=3.
// Changes vs round 4:
//  - x pre-transposed+padded to xt[b][z34][y34][w34][ch128] f16 (prep_xt) so the
//    slab is staged with 41 global_load_lds_dwordx4 per block (pre-swizzled src,
//    linear LDS dest) instead of ~100 scalar ds_write_b16 per thread.
//  - zero zy-row dropped (tap27 B-weights are zero; A-side clamped to row 0).
//  - votes/RT/LG overlay the slab after a post-K-loop barrier: LDS 79360->41984 B
//    -> 3 blocks/CU (was 2).
//  - XCD-contiguous blockIdx swizzle (4096 = 8 XCDs x 512) for xt L2 locality.

typedef _Float16 half8 __attribute__((ext_vector_type(8)));
typedef float f32x4 __attribute__((ext_vector_type(4)));

__device__ __forceinline__ void gload_lds16(const void* g, void* l) {
    __builtin_amdgcn_global_load_lds(
        (const __attribute__((address_space(1))) void*)g,
        (__attribute__((address_space(3))) void*)l, 16, 0, 0);
}

// ---- prep 1: cw f32 (n=128, ca=16, tap=27) -> wh2 f16 [n][c=14][k=32], k = tp*16+ca,
//      tap = 2c+tp, tap 27 zeroed. ----
__global__ __launch_bounds__(256) void prep_weights(const float* __restrict__ cw,
                                                    _Float16* __restrict__ wh2) {
    const int idx = blockIdx.x * 256 + threadIdx.x;   // 57344
    const int n   = idx / 448;
    const int rem = idx - n * 448;
    const int c   = rem >> 5;
    const int k   = rem & 31;
    const int tp  = k >> 4, ca = k & 15;
    const int tap = 2 * c + tp;
    float v = (tap < 27) ? cw[n * 432 + ca * 27 + tap] : 0.0f;
    wh2[idx] = (_Float16)v;
}

// ---- prep 2: x (2,128,32,32,32) f32 -> xt[b][zp34][yp34][wp34][ch128] f16,
//      1-voxel zero-padded halo on z,y,w. Coalesced 16B writes; scalar ch reads. ----
__global__ __launch_bounds__(256) void prep_xt(const float* __restrict__ x,
                                               _Float16* __restrict__ xt) {
    const int idx = blockIdx.x * 256 + threadIdx.x;   // 1,257,728 = 2*34^3*16
    const int u   = idx & 15;
    const int vox = idx >> 4;
    const int wp  = vox % 34;
    const int t2  = vox / 34;
    const int yp  = t2 % 34;
    const int t3  = t2 / 34;
    const int zp  = t3 % 34;
    const int b   = t3 / 34;
    half8 hv = (half8)(_Float16)0.f;
    if (zp >= 1 && zp <= 32 && yp >= 1 && yp <= 32 && wp >= 1 && wp <= 32) {
        const float* sp = x + (size_t)(b * 128 + u * 8) * 32768
                            + (zp - 1) * 1024 + (yp - 1) * 32 + (wp - 1);
        #pragma unroll
        for (int e = 0; e < 8; e++) hv[e] = (_Float16)sp[(size_t)e * 32768];
    }
    *(half8*)(xt + (size_t)idx * 8) = hv;
}

__global__ __launch_bounds__(256, 3) void caps_mfma_kernel(
    const _Float16* __restrict__ xt,  // (2,34,34,34,128) f16 padded
    const _Float16* __restrict__ wh2, // (128,14,32) f16 reordered
    const float* __restrict__ cb,     // (128,)
    const float* __restrict__ bias,   // (8,16)
    float* __restrict__ out)          // (2,8,16,32,32,32) f32
{
    // 41,984 B: slab = 164 rows x 256B (rows 0..161 live: zy0..8 x j0..17;
    // 162/163 are write-phantoms). Votes (33,024B) + RT/LG overlay after B1.
    __shared__ half8 slabv[2624];
    char* smem = (char*)slabv;
    _Float16* Vh = (_Float16*)slabv;
    float* RT = (float*)slabv;
    float* LG = (float*)slabv + 1152;

    const int t  = threadIdx.x;
    const int bx = blockIdx.x;
    const int gid = ((bx & 7) << 9) | (bx >> 3);   // XCD-contiguous (4096 = 8*512)
    const int wseg = gid & 1;
    const int h    = (gid >> 1) & 31;
    const int d    = (gid >> 6) & 31;
    const int b    = gid >> 11;
    const int w0g  = wseg << 4;

    const int wid = t >> 6, lane = t & 63;

    // ================= stage slab: 162 rows x 256B via global_load_lds ============
    // row rr = zy*18 + j holds, at slot s, ch-unit u = s ^ (j&15) (inverse-swizzled
    // source, linear LDS dest). One instruction = 4 rows (64 lanes x 16B).
    {
        const int lrow = lane >> 4;        // 0..3
        const int s    = lane & 15;
        const int bzd  = b * 34 + d;
        for (int i = wid; i < 41; i += 4) {
            const int rr0 = i << 2;
            const int rr  = rr0 + lrow;
            int zy = (rr * 57) >> 10;      // rr/18, exact for rr<162
            int j  = rr - zy * 18;
            if (zy > 8) { zy = 0; j = 0; } // phantom rows 162/163: any valid src
            const int dz = (zy * 11) >> 5; // zy/3
            const int dy = zy - dz * 3;
            const int uu = s ^ (j & 15);
            const unsigned off =
                ((((unsigned)(bzd + dz) * 34u + (unsigned)(h + dy)) * 34u
                  + (unsigned)(w0g + j)) << 8) + (unsigned)(uu << 4);
            gload_lds16((const char*)xt + off, smem + (rr0 << 8));
        }
    }
    __syncthreads();   // B0: vmcnt drained by barrier -> slab staged

    // ================= GEMM: 8 id-GEMMs, N=128, K=448 (14 chunks), no inner barriers
    const int q = lane >> 4, r = lane & 15;
    const int wy = wid >> 1, wx = wid & 1;
    const int qlow = q & 1, tphase = q >> 1;

    int zyA[14], dxA[14];
    #pragma unroll
    for (int c = 0; c < 14; c++) {
        int tap = 2 * c + tphase;          // 0..27
        if (tap > 26) tap = 0;             // tap27: B weights are zero -> any finite A
        const int dz = tap / 9, r9 = tap - dz * 9;
        const int dy = r9 / 3,  dxx = r9 - dy * 3;
        zyA[c] = dz * 3 + dy;
        dxA[c] = dxx;
    }
    int uA[4];
    #pragma unroll
    for (int mt = 0; mt < 4; mt++) uA[mt] = (wy * 4 + mt) * 2 + qlow;

    const _Float16* bp[4];
    #pragma unroll
    for (int nt = 0; nt < 4; nt++)
        bp[nt] = wh2 + (wx * 64 + nt * 16 + r) * 448 + q * 8;

    f32x4 acc[4][4];
    #pragma unroll
    for (int i = 0; i < 4; i++)
        #pragma unroll
        for (int j = 0; j < 4; j++) acc[i][j] = (f32x4)0.f;

    #pragma unroll
    for (int c = 0; c < 14; c++) {
        half8 bf[4], af[4];
        #pragma unroll
        for (int nt = 0; nt < 4; nt++)
            bf[nt] = *(const half8*)(bp[nt] + c * 32);
        const int jw = r + dxA[c];
        const int rowb = zyA[c] * 4608 + jw * 256;
        const int js = jw & 15;
        #pragma unroll
        for (int mt = 0; mt < 4; mt++)
            af[mt] = *(const half8*)(smem + rowb + ((uA[mt] ^ js) << 4));
        #pragma unroll
        for (int mt = 0; mt < 4; mt++)
            #pragma unroll
            for (int nt = 0; nt < 4; nt++)
                acc[mt][nt] = __builtin_amdgcn_mfma_f32_16x16x32_f16(
                    af[mt], bf[nt], acc[mt][nt], 0, 0, 0);
    }

    __syncthreads();   // B1: all slab reads done -> votes may overlay the slab

    // ================= epilogue: votes (+conv bias) f16, overlaying the slab =======
    float cbv[4];
    #pragma unroll
    for (int nt = 0; nt < 4; nt++) cbv[nt] = cb[wx * 64 + nt * 16 + r];
    #pragma unroll
    for (int mt = 0; mt < 4; mt++) {
        #pragma unroll
        for (int nt = 0; nt < 4; nt++) {
            const int n = wx * 64 + nt * 16 + r;
            #pragma unroll
            for (int reg = 0; reg < 4; reg++) {
                const int v = q * 4 + reg;          // C/D row = q*4+reg
                const int i = wy * 4 + mt;
                Vh[v * 1032 + i * 128 + n] = (_Float16)(acc[mt][nt][reg] + cbv[nt]);
            }
        }
    }
    __syncthreads();   // B2: all vote writes visible

    // ================= routing: 256 threads = 128 (v,o) pairs x 2 halves ===========
    const int p = t >> 1, half = t & 1;
    const int vv = p & 15, oo = p >> 4;   // also coop-softmax task (v2=vv, i2=oo)

    float vf[8][8];
    #pragma unroll
    for (int i = 0; i < 8; i++) {
        const half8 hv = *(const half8*)&Vh[vv * 1032 + i * 128 + oo * 16 + half * 8];
        #pragma unroll
        for (int a = 0; a < 8; a++) vf[i][a] = (float)hv[a];
    }
    __syncthreads();   // B3: vote reads done -> RT/LG may overlay vote region

    float vn[8];
    #pragma unroll
    for (int i = 0; i < 8; i++) {
        float s = 0.f;
        #pragma unroll
        for (int a = 0; a < 8; a++) s = fmaf(vf[i][a], vf[i][a], s);
        const float so = __shfl_xor(s, 1);
        vn[i] = sqrtf(s + so);
    }
    float bl[8];
    #pragma unroll
    for (int a = 0; a < 8; a++) bl[a] = bias[oo * 16 + half * 8 + a];

    float rt[8], lgr[8], pre[8];
    #pragma unroll
    for (int i = 0; i < 8; i++) { rt[i] = 0.125f; lgr[i] = 0.f; }

    for (int it = 0; it < 3; it++) {
        #pragma unroll
        for (int a = 0; a < 8; a++) {
            float s = bl[a];
            #pragma unroll
            for (int i = 0; i < 8; i++) s = fmaf(rt[i], vf[i][a], s);
            pre[a] = s;
        }
        if (it == 2) break;

        float s2 = 0.f;
        #pragma unroll
        for (int a = 0; a < 8; a++) s2 = fmaf(pre[a], pre[a], s2);
        const float pn = sqrtf(s2 + __shfl_xor(s2, 1));

        #pragma unroll
        for (int i = 0; i < 8; i++) {
            float dp = 0.f;
            #pragma unroll
            for (int a = 0; a < 8; a++) dp = fmaf(pre[a], vf[i][a], dp);
            const float dot = dp + __shfl_xor(dp, 1);
            lgr[i] += __fdividef(dot, fmaxf(pn * vn[i], 1e-8f));
        }
        if (half == 0) {
            #pragma unroll
            for (int i = 0; i < 8; i++) LG[vv * 72 + i * 8 + oo] = lgr[i];
        }
        __syncthreads();   // LG writes visible

        // coop softmax over o for task (v2=vv, i2=oo); |logit| <= 2 -> no max-sub
        {
            const f32x4 E = *(const f32x4*)&LG[vv * 72 + oo * 8 + half * 4];
            f32x4 ex; float ps = 0.f;
            #pragma unroll
            for (int k = 0; k < 4; k++) { ex[k] = __expf(E[k]); ps += ex[k]; }
            const float sum = ps + __shfl_xor(ps, 1);
            const float rs = __fdividef(1.f, sum);
            f32x4 w4;
            #pragma unroll
            for (int k = 0; k < 4; k++) w4[k] = ex[k] * rs;
            *(f32x4*)&RT[vv * 72 + oo * 8 + half * 4] = w4;
        }
        __syncthreads();   // RT writes visible

        #pragma unroll
        for (int i = 0; i < 8; i++) rt[i] = RT[vv * 72 + i * 8 + oo];
    }

    // ---- squash + store ----
    float s2 = 0.f;
    #pragma unroll
    for (int a = 0; a < 8; a++) s2 = fmaf(pre[a], pre[a], s2);
    const float n2 = s2 + __shfl_xor(s2, 1);
    const float nn = sqrtf(n2);
    const float scale = __fdividef(n2, (1.f + n2) * (nn + 1e-12f));
    const size_t sp = (size_t)d * 1024 + h * 32 + w0g + vv;
    #pragma unroll
    for (int a = 0; a < 8; a++)
        out[((size_t)((b * 8 + oo) * 16 + half * 8 + a)) * 32768 + sp] = pre[a] * scale;
}

extern "C" void kernel_launch(void* const* d_in, const int* in_sizes, int n_in,
                              void* d_out, int out_size, void* d_ws, size_t ws_size,
                              hipStream_t stream) {
    const float* x    = (const float*)d_in[0];
    const float* cw   = (const float*)d_in[1];
    const float* cb   = (const float*)d_in[2];
    const float* bias = (const float*)d_in[3];
    float* out = (float*)d_out;
    _Float16* wh2 = (_Float16*)d_ws;                     // 114,688 B
    _Float16* xt  = (_Float16*)((char*)d_ws + 114688);   // 20,123,648 B (ws >= 20.3 MB)

    hipLaunchKernelGGL(prep_weights, dim3(224), dim3(256), 0, stream, cw, wh2);
    hipLaunchKernelGGL(prep_xt, dim3(4913), dim3(256), 0, stream, x, xt);
    hipLaunchKernelGGL(caps_mfma_kernel, dim3(4096), dim3(256), 0, stream,
                       xt, wh2, cb, bias, out);
}

// Round 3
// 214.117 us; speedup vs baseline: 1.4842x; 1.0424x over previous
//
#include <hip/hip_runtime.h>
#include <math.h>

// ConvSlimCapsule3D fused, round 7 (= round 6 + staging-tail race removed).
// Shapes fixed: B=2, in_dim=8, in_atoms=16, D=H=W=32, out_dim=8, out_atoms=16, k=3.
//  - prep_xt: coalesced LDS-transpose (one block per (b,zp,yp) plane).
//  - caps kernel: 32 voxels/block (full w row). 512 threads / 8 waves, M=256.
//    Slab = 9zy x 34j x 256B (+2 phantom rows) = 78,848B -> 2 blocks/CU x 8 waves
//    = 16 waves/CU. Staging: 77 global_load_lds_dwordx4 rounds, each LDS byte has
//    exactly ONE writer (phantom rows 306/307 clamp to a valid source).
//    Votes (66,048B) overlay slab after B1; RT/LG overlay votes after B3.

typedef _Float16 half8 __attribute__((ext_vector_type(8)));
typedef float f32x4 __attribute__((ext_vector_type(4)));

__device__ __forceinline__ void gload_lds16(const void* g, void* l) {
    __builtin_amdgcn_global_load_lds(
        (const __attribute__((address_space(1))) void*)g,
        (__attribute__((address_space(3))) void*)l, 16, 0, 0);
}

// ---- prep 1: cw f32 (n=128, ca=16, tap=27) -> wh2 f16 [n][c=14][k=32], k = tp*16+ca,
//      tap = 2c+tp, tap 27 zeroed. ----
__global__ __launch_bounds__(256) void prep_weights(const float* __restrict__ cw,
                                                    _Float16* __restrict__ wh2) {
    const int idx = blockIdx.x * 256 + threadIdx.x;   // 57344
    const int n   = idx / 448;
    const int rem = idx - n * 448;
    const int c   = rem >> 5;
    const int k   = rem & 31;
    const int tp  = k >> 4, ca = k & 15;
    const int tap = 2 * c + tp;
    float v = (tap < 27) ? cw[n * 432 + ca * 27 + tap] : 0.0f;
    wh2[idx] = (_Float16)v;
}

// ---- prep 2: x (2,128,32,32,32) f32 -> xt[b][zp34][yp34][wp34][ch128] f16,
//      1-voxel zero halo. One block per (b,zp,yp) plane; LDS transpose.
//      Reads coalesced along w; writes coalesced ch-contiguous. ----
__global__ __launch_bounds__(256) void prep_xt(const float* __restrict__ x,
                                               _Float16* __restrict__ xt) {
    __shared__ half8 ldsv[544];           // [wp 0..33][ch 0..127] f16 = 8704 B
    _Float16* lds = (_Float16*)ldsv;
    const int t  = threadIdx.x;
    const int bz = blockIdx.x;            // 2*34*34 = 2312
    const int yp = bz % 34;
    const int t2 = bz / 34;
    const int zp = t2 % 34;
    const int b  = t2 / 34;
    _Float16* dst = xt + (size_t)(((b * 34 + zp) * 34 + yp)) * 34 * 128;
    const bool interior = (zp >= 1 && zp <= 32 && yp >= 1 && yp <= 32);
    if (!interior) {
        const half8 z8 = (half8)(_Float16)0.f;
        for (int idx = t; idx < 544; idx += 256)
            *(half8*)(dst + idx * 8) = z8;
        return;
    }
    const int c  = t >> 1;                // 0..127
    const int wh = (t & 1) << 4;          // 0 or 16
    const float* sp = x + (size_t)(b * 128 + c) * 32768
                        + (zp - 1) * 1024 + (yp - 1) * 32 + wh;
    #pragma unroll
    for (int e4 = 0; e4 < 4; e4++) {
        const f32x4 v = *(const f32x4*)(sp + e4 * 4);
        #pragma unroll
        for (int e = 0; e < 4; e++)
            lds[(wh + e4 * 4 + e + 1) * 128 + c] = (_Float16)v[e];
    }
    if (t < 128) lds[t] = (_Float16)0.f;                // wp = 0
    else         lds[33 * 128 + (t - 128)] = (_Float16)0.f; // wp = 33
    __syncthreads();
    for (int idx = t; idx < 544; idx += 256)
        *(half8*)(dst + idx * 8) = *(const half8*)(lds + idx * 8);
}

__global__ __launch_bounds__(512, 4) void caps_mfma_kernel(
    const _Float16* __restrict__ xt,  // (2,34,34,34,128) f16 padded
    const _Float16* __restrict__ wh2, // (128,14,32) f16 reordered
    const float* __restrict__ cb,     // (128,)
    const float* __restrict__ bias,   // (8,16)
    float* __restrict__ out)          // (2,8,16,32,32,32) f32
{
    // 78,848 B: slab = 306 live rows (zy 0..8 x j 0..33) + 2 phantom, x 256B.
    __shared__ half8 slabv[4928];
    char* smem = (char*)slabv;
    _Float16* Vh = (_Float16*)slabv;
    float* RT = (float*)slabv;
    float* LG = (float*)slabv + 2304;

    const int t  = threadIdx.x;
    const int bx = blockIdx.x;
    const int gid = ((bx & 7) << 8) | (bx >> 3);   // XCD-contiguous (2048 = 8*256)
    const int h = gid & 31;
    const int d = (gid >> 5) & 31;
    const int b = gid >> 10;

    const int wid = t >> 6, lane = t & 63;

    // ================= stage slab: 308 rows x 256B via global_load_lds ============
    // row rr = zy*34 + j holds, at slot s, ch-unit u = s ^ (j&15). One instruction
    // = 4 rows; phantom rows 306/307 read a valid source (data unused).
    {
        const int lrow = lane >> 4;        // 0..3
        const int s    = lane & 15;
        const int bzd  = b * 34 + d;
        for (int i = wid; i < 77; i += 8) {
            const int rr0 = i << 2;        // 0..304
            const int rr  = rr0 + lrow;    // 0..307
            int zy = rr / 34;              // 0..9
            int j  = rr - zy * 34;
            if (rr >= 306) { zy = 0; j = 0; }   // phantom
            const int dz  = (zy * 11) >> 5; // zy/3 for zy<=8
            const int dy  = zy - dz * 3;
            const int uu  = s ^ (j & 15);
            const unsigned off =
                ((((unsigned)(bzd + dz) * 34u + (unsigned)(h + dy)) * 34u
                  + (unsigned)j) << 8) + (unsigned)(uu << 4);
            gload_lds16((const char*)xt + off, smem + (rr0 << 8));
        }
    }
    __syncthreads();   // B0: vmcnt drained by barrier -> slab staged

    // ================= GEMM: M=256, N=128, K=448 (14 chunks), no inner barriers ===
    const int q = lane >> 4, r = lane & 15;
    const int wy = wid >> 1, wx = wid & 1;
    const int qlow = q & 1, tphase = q >> 1;

    int zyA[14], dxA[14];
    #pragma unroll
    for (int c = 0; c < 14; c++) {
        int tap = 2 * c + tphase;          // 0..27
        if (tap > 26) tap = 0;             // tap27: B weights are zero
        const int dz = tap / 9, r9 = tap - dz * 9;
        const int dy = r9 / 3,  dxx = r9 - dy * 3;
        zyA[c] = dz * 3 + dy;
        dxA[c] = dxx;
    }
    int uA[4], vh16[4];
    #pragma unroll
    for (int mt = 0; mt < 4; mt++) {
        const int mm = wy * 4 + mt;        // m-tile 0..15: in_dim = mm>>1, vhalf = mm&1
        uA[mt]   = ((mm >> 1) << 1) + qlow;
        vh16[mt] = (mm & 1) << 4;
    }

    const _Float16* bp[4];
    #pragma unroll
    for (int nt = 0; nt < 4; nt++)
        bp[nt] = wh2 + (wx * 64 + nt * 16 + r) * 448 + q * 8;

    f32x4 acc[4][4];
    #pragma unroll
    for (int i = 0; i < 4; i++)
        #pragma unroll
        for (int j = 0; j < 4; j++) acc[i][j] = (f32x4)0.f;

    #pragma unroll
    for (int c = 0; c < 14; c++) {
        half8 bf[4], af[4];
        #pragma unroll
        for (int nt = 0; nt < 4; nt++)
            bf[nt] = *(const half8*)(bp[nt] + c * 32);
        #pragma unroll
        for (int mt = 0; mt < 4; mt++) {
            const int jw = vh16[mt] + r + dxA[c];
            const int js = jw & 15;
            af[mt] = *(const half8*)(smem + zyA[c] * 8704 + jw * 256
                                          + ((uA[mt] ^ js) << 4));
        }
        #pragma unroll
        for (int mt = 0; mt < 4; mt++)
            #pragma unroll
            for (int nt = 0; nt < 4; nt++)
                acc[mt][nt] = __builtin_amdgcn_mfma_f32_16x16x32_f16(
                    af[mt], bf[nt], acc[mt][nt], 0, 0, 0);
    }

    __syncthreads();   // B1: all slab reads done -> votes may overlay the slab

    // ================= epilogue: votes (+conv bias) f16, overlaying the slab =======
    float cbv[4];
    #pragma unroll
    for (int nt = 0; nt < 4; nt++) cbv[nt] = cb[wx * 64 + nt * 16 + r];
    #pragma unroll
    for (int mt = 0; mt < 4; mt++) {
        const int id = (wy * 4 + mt) >> 1;     // in_dim
        const int vb = vh16[mt];               // voxel-half base
        #pragma unroll
        for (int nt = 0; nt < 4; nt++) {
            const int n = wx * 64 + nt * 16 + r;
            #pragma unroll
            for (int reg = 0; reg < 4; reg++) {
                const int v = vb + q * 4 + reg;     // voxel 0..31
                Vh[v * 1032 + id * 128 + n] = (_Float16)(acc[mt][nt][reg] + cbv[nt]);
            }
        }
    }
    __syncthreads();   // B2: all vote writes visible

    // ================= routing: 512 threads = 256 (v,o) pairs x 2 halves ===========
    const int p = t >> 1, half = t & 1;
    const int vv = p & 31, oo = p >> 5;   // also coop-softmax task (v2=vv, i2=oo)

    float vf[8][8];
    #pragma unroll
    for (int i = 0; i < 8; i++) {
        const half8 hv = *(const half8*)&Vh[vv * 1032 + i * 128 + oo * 16 + half * 8];
        #pragma unroll
        for (int a = 0; a < 8; a++) vf[i][a] = (float)hv[a];
    }
    __syncthreads();   // B3: vote reads done -> RT/LG may overlay vote region

    float vn[8];
    #pragma unroll
    for (int i = 0; i < 8; i++) {
        float s = 0.f;
        #pragma unroll
        for (int a = 0; a < 8; a++) s = fmaf(vf[i][a], vf[i][a], s);
        const float so = __shfl_xor(s, 1);
        vn[i] = sqrtf(s + so);
    }
    float bl[8];
    #pragma unroll
    for (int a = 0; a < 8; a++) bl[a] = bias[oo * 16 + half * 8 + a];

    float rt[8], lgr[8], pre[8];
    #pragma unroll
    for (int i = 0; i < 8; i++) { rt[i] = 0.125f; lgr[i] = 0.f; }

    for (int it = 0; it < 3; it++) {
        #pragma unroll
        for (int a = 0; a < 8; a++) {
            float s = bl[a];
            #pragma unroll
            for (int i = 0; i < 8; i++) s = fmaf(rt[i], vf[i][a], s);
            pre[a] = s;
        }
        if (it == 2) break;

        float s2 = 0.f;
        #pragma unroll
        for (int a = 0; a < 8; a++) s2 = fmaf(pre[a], pre[a], s2);
        const float pn = sqrtf(s2 + __shfl_xor(s2, 1));

        #pragma unroll
        for (int i = 0; i < 8; i++) {
            float dp = 0.f;
            #pragma unroll
            for (int a = 0; a < 8; a++) dp = fmaf(pre[a], vf[i][a], dp);
            const float dot = dp + __shfl_xor(dp, 1);
            lgr[i] += __fdividef(dot, fmaxf(pn * vn[i], 1e-8f));
        }
        if (half == 0) {
            #pragma unroll
            for (int i = 0; i < 8; i++) LG[vv * 72 + i * 8 + oo] = lgr[i];
        }
        __syncthreads();   // LG writes visible

        // coop softmax over o for task (v2=vv, i2=oo); |logit| <= 2 -> no max-sub
        {
            const f32x4 E = *(const f32x4*)&LG[vv * 72 + oo * 8 + half * 4];
            f32x4 ex; float ps = 0.f;
            #pragma unroll
            for (int k = 0; k < 4; k++) { ex[k] = __expf(E[k]); ps += ex[k]; }
            const float sum = ps + __shfl_xor(ps, 1);
            const float rs = __fdividef(1.f, sum);
            f32x4 w4;
            #pragma unroll
            for (int k = 0; k < 4; k++) w4[k] = ex[k] * rs;
            *(f32x4*)&RT[vv * 72 + oo * 8 + half * 4] = w4;
        }
        __syncthreads();   // RT writes visible

        #pragma unroll
        for (int i = 0; i < 8; i++) rt[i] = RT[vv * 72 + i * 8 + oo];
    }

    // ---- squash + store ----
    float s2 = 0.f;
    #pragma unroll
    for (int a = 0; a < 8; a++) s2 = fmaf(pre[a], pre[a], s2);
    const float n2 = s2 + __shfl_xor(s2, 1);
    const float nn = sqrtf(n2);
    const float scale = __fdividef(n2, (1.f + n2) * (nn + 1e-12f));
    const size_t sp = (size_t)d * 1024 + h * 32 + vv;
    #pragma unroll
    for (int a = 0; a < 8; a++)
        out[((size_t)((b * 8 + oo) * 16 + half * 8 + a)) * 32768 + sp] = pre[a] * scale;
}

extern "C" void kernel_launch(void* const* d_in, const int* in_sizes, int n_in,
                              void* d_out, int out_size, void* d_ws, size_t ws_size,
                              hipStream_t stream) {
    const float* x    = (const float*)d_in[0];
    const float* cw   = (const float*)d_in[1];
    const float* cb   = (const float*)d_in[2];
    const float* bias = (const float*)d_in[3];
    float* out = (float*)d_out;
    _Float16* wh2 = (_Float16*)d_ws;                     // 114,688 B
    _Float16* xt  = (_Float16*)((char*)d_ws + 114688);   // 20,123,648 B

    hipLaunchKernelGGL(prep_weights, dim3(224), dim3(256), 0, stream, cw, wh2);
    hipLaunchKernelGGL(prep_xt, dim3(2312), dim3(256), 0, stream, x, xt);
    hipLaunchKernelGGL(caps_mfma_kernel, dim3(2048), dim3(512), 0, stream,
                       xt, wh2, cb, bias, out);
}